// Round 17
// baseline (21.432 us; speedup 1.0000x reference)
//
#include <hip/hip_runtime.h>

#define TPB 64          // one wave per block — wave-synchronous, no barriers
#define OSTR 52         // padded overlay stride (floats): 208 B, 16B-aligned

typedef float __attribute__((ext_vector_type(4))) f32x4;

struct M3 { float a[9]; };
struct V3 { float x, y, z; };

__device__ __forceinline__ void fence_lgkm() {
    asm volatile("s_waitcnt lgkmcnt(0)" ::: "memory");
    __builtin_amdgcn_wave_barrier();
}

// rotation from 6 floats held in three float2 registers
__device__ __forceinline__ M3 rot6d2(const float2* v) {
    float x0 = v[0].x, x1 = v[0].y, x2 = v[1].x;
    float y0 = v[1].y, y1 = v[2].x, y2 = v[2].y;
    float inx = rsqrtf(fmaxf(x0*x0 + x1*x1 + x2*x2, 1e-16f));
    x0 *= inx; x1 *= inx; x2 *= inx;
    float z0 = x1*y2 - x2*y1;
    float z1 = x2*y0 - x0*y2;
    float z2 = x0*y1 - x1*y0;
    float inz = rsqrtf(fmaxf(z0*z0 + z1*z1 + z2*z2, 1e-16f));
    z0 *= inz; z1 *= inz; z2 *= inz;
    float w0 = z1*x2 - z2*x1;
    float w1 = z2*x0 - z0*x2;
    float w2 = z0*x1 - z1*x0;
    M3 R;
    R.a[0] = x0; R.a[1] = w0; R.a[2] = z0;
    R.a[3] = x1; R.a[4] = w1; R.a[5] = z1;
    R.a[6] = x2; R.a[7] = w2; R.a[8] = z2;
    return R;
}

__device__ __forceinline__ M3 m3mul(const M3& A, const M3& B) {
    M3 C;
#pragma unroll
    for (int r = 0; r < 3; ++r)
#pragma unroll
        for (int c = 0; c < 3; ++c)
            C.a[3*r + c] = A.a[3*r + 0] * B.a[0 + c]
                         + A.a[3*r + 1] * B.a[3 + c]
                         + A.a[3*r + 2] * B.a[6 + c];
    return C;
}

__device__ __forceinline__ V3 step(const M3& P, V3 pp, int axis, float s) {
    V3 q;
    q.x = pp.x + s * P.a[0 + axis];
    q.y = pp.y + s * P.a[3 + axis];
    q.z = pp.z + s * P.a[6 + axis];
    return q;
}

__device__ __forceinline__ void put(float* so, int j, V3 q) {
    so[3*j + 0] = q.x; so[3*j + 1] = q.y; so[3*j + 2] = q.z;
}

// FK from per-joint register float2 triples -> LDS overlay slice `so`.
// v[u] maps to joints {0,1,2,4,5,7,8,9,11,12,14,15}.
__device__ __forceinline__ void fk_from_regs(const float2 v[12][3], float* so,
                                             const float* len,
                                             float rx, float ry, float rz) {
    V3 q0; q0.x = rx; q0.y = ry; q0.z = rz;
    so[0] = rx; so[1] = ry; so[2] = rz;
    M3 W0 = rot6d2(v[0]);

    M3 W1 = m3mul(W0, rot6d2(v[1]));  V3 q1 = step(W0, q0, 0, -len[0]);  put(so, 1, q1);
    M3 W2 = m3mul(W1, rot6d2(v[2]));  V3 q2 = step(W1, q1, 1, -len[1]);  put(so, 2, q2);
    /* leaf 3 */                      V3 q3 = step(W2, q2, 1, -len[2]);  put(so, 3, q3);

    M3 W4 = m3mul(W0, rot6d2(v[3]));  V3 q4 = step(W0, q0, 0,  len[3]);  put(so, 4, q4);
    M3 W5 = m3mul(W4, rot6d2(v[4]));  V3 q5 = step(W4, q4, 1, -len[4]);  put(so, 5, q5);
    /* leaf 6 */                      V3 q6 = step(W5, q5, 1, -len[5]);  put(so, 6, q6);

    M3 W7 = m3mul(W0, rot6d2(v[5]));  V3 q7 = step(W0, q0, 1,  len[6]);  put(so, 7, q7);
    M3 W8 = m3mul(W7, rot6d2(v[6]));  V3 q8 = step(W7, q7, 1,  len[7]);  put(so, 8, q8);

    M3 W9 = m3mul(W8, rot6d2(v[7]));  V3 q9 = step(W8, q8, 1,  len[8]);  put(so, 9, q9);
    /* leaf 10 */                     V3 q10 = step(W9, q9, 1, len[9]);  put(so, 10, q10);

    M3 W11 = m3mul(W8,  rot6d2(v[8]));  V3 q11 = step(W8,  q8,  0, len[10]); put(so, 11, q11);
    M3 W12 = m3mul(W11, rot6d2(v[9]));  V3 q12 = step(W11, q11, 0, len[11]); put(so, 12, q12);
    /* leaf 13 */                       V3 q13 = step(W12, q12, 0, len[12]); put(so, 13, q13);

    M3 W14 = m3mul(W8,  rot6d2(v[10])); V3 q14 = step(W8,  q8,  0, -len[13]); put(so, 14, q14);
    M3 W15 = m3mul(W14, rot6d2(v[11])); V3 q15 = step(W14, q14, 0, -len[14]); put(so, 15, q15);
    /* leaf 16 */                       V3 q16 = step(W15, q15, 0, -len[15]); put(so, 16, q16);
}

__device__ __forceinline__ void load_sample(const float* __restrict__ rot,
                                            long long gs, float2 v[12][3]) {
    constexpr int UJ[12] = {0, 1, 2, 4, 5, 7, 8, 9, 11, 12, 14, 15};
    const float2* g2 = (const float2*)(rot + (size_t)gs * 102);   // 8B-aligned
#pragma unroll
    for (int u = 0; u < 12; ++u)
#pragma unroll
        for (int k = 0; k < 3; ++k)
            v[u][k] = g2[UJ[u] * 3 + k];
}

__global__ __launch_bounds__(TPB, 4) void PoseDecoder_kernel(
    const float* __restrict__ rot,    // [BL,17,6]
    const float* __restrict__ bones,  // [B,16]
    const float* __restrict__ root,   // [BL,3]
    float* __restrict__ out,          // [BL,17,3]
    int BL, int L)
{
    __shared__ __align__(16) float s_out[TPB * OSTR];   // 13312 B padded overlay
    const int t = threadIdx.x;
    const long long base = (long long)blockIdx.x * TPB;
    const long long gs = base + t;

    const bool fast = (base + TPB <= BL) &&
                      (base / L == (base + TPB - 1) / L);

    if (fast) {
        // ---- per-lane scattered loads straight to registers ----
        float2 v[12][3];
        load_sample(rot, gs, v);
        float rx = root[gs*3 + 0], ry = root[gs*3 + 1], rz = root[gs*3 + 2];

        // one bone group per block -> scalar loads (SGPRs)
        const float* bl = bones + (size_t)(base / L) * 16;
        float len[16];
#pragma unroll
        for (int k = 0; k < 16; ++k) len[k] = bl[k];

        // ---- FK from registers, results into padded LDS overlay ----
        fk_from_regs(v, s_out + t * OSTR, len, rx, ry, rz);
        fence_lgkm();                   // overlay writes visible wave-wide

        // ---- LDS -> global nontemporal store of the packed [64][51] image ----
        float* o = out + (size_t)base * 51;
#pragma unroll
        for (int r = 0; r < 13; ++r) {
            int f = r * 64 + t;                 // float4 index in packed image
            if (r < 12 || t < 48) {             // 816 total
                int e0 = f * 4;
                int s0 = e0 / 51, m0 = e0 - s0 * 51;
                float a0 = s_out[s0 * OSTR + m0];
                int e1 = e0 + 1; int s1 = e1 / 51, m1 = e1 - s1 * 51;
                float a1 = s_out[s1 * OSTR + m1];
                int e2 = e0 + 2; int s2 = e2 / 51, m2 = e2 - s2 * 51;
                float a2 = s_out[s2 * OSTR + m2];
                int e3 = e0 + 3; int s3 = e3 / 51, m3 = e3 - s3 * 51;
                float a3 = s_out[s3 * OSTR + m3];
                f32x4 w = {a0, a1, a2, a3};
                __builtin_nontemporal_store(w, (f32x4*)(o + e0));
            }
        }
    } else {
        // generic fallback (partial block / bone-boundary crossing)
        if (gs < BL) {
            float2 v[12][3];
            load_sample(rot, gs, v);
            float rx = root[gs*3+0], ry = root[gs*3+1], rz = root[gs*3+2];
            const float* bl = bones + (size_t)(gs / L) * 16;
            float len[16];
#pragma unroll
            for (int k = 0; k < 16; ++k) len[k] = bl[k];
            float so[51];
            fk_from_regs(v, so, len, rx, ry, rz);
            for (int m = 0; m < 51; ++m) out[gs * 51 + m] = so[m];  // slow, correct
        }
    }
}

extern "C" void kernel_launch(void* const* d_in, const int* in_sizes, int n_in,
                              void* d_out, int out_size, void* d_ws, size_t ws_size,
                              hipStream_t stream) {
    const float* rot   = (const float*)d_in[0];
    const float* bones = (const float*)d_in[1];
    const float* root  = (const float*)d_in[2];
    float* out = (float*)d_out;

    int BL = in_sizes[0] / 102;     // 17 joints * 6
    int B  = in_sizes[1] / 16;      // 16 bones
    int L  = BL / B;

    int grid = (BL + TPB - 1) / TPB;
    PoseDecoder_kernel<<<grid, TPB, 0, stream>>>(rot, bones, root, out, BL, L);
}